// Round 2
// baseline (496.360 us; speedup 1.0000x reference)
//
#include <hip/hip_runtime.h>

typedef unsigned short u16;
typedef __attribute__((ext_vector_type(8))) __bf16 bf16x8;
typedef __attribute__((ext_vector_type(4))) float floatx4;

__device__ inline float bf2f(u16 u) {
  union { unsigned u; float f; } v; v.u = ((unsigned)u) << 16; return v.f;
}
__device__ inline u16 f2bf(float f) {
  union { float f; unsigned u; } v; v.f = f;
  unsigned r = v.u + 0x7fffu + ((v.u >> 16) & 1u);
  return (u16)(r >> 16);
}

__device__ inline void glds16(const u16* g, u16* l) {
  __builtin_amdgcn_global_load_lds((const __attribute__((address_space(1))) void*)g,
                                   (__attribute__((address_space(3))) void*)l, 16, 0, 0);
}

// ---------------- dtype probe: fp32-as-u16 halves have wild exponents ----------------
__global__ __launch_bounds__(256) void detect_k(const u16* __restrict__ w, int* flag)
{
  __shared__ int cnt;
  if (threadIdx.x == 0) cnt = 0;
  __syncthreads();
  int c = 0;
  for (int i = threadIdx.x; i < 16384; i += 256) {
    const int e = (w[i] >> 7) & 0xFF;
    if (e < 64 || e > 191) ++c;
  }
  atomicAdd(&cnt, c);
  __syncthreads();
  if (threadIdx.x == 0) *flag = (cnt > 256) ? 1 : 0;   // 1 => inputs are fp32
}

// ---------------- x -> bf16 (copy or downcast), 4 elems/thread ----------------
__global__ __launch_bounds__(256) void cast_x_k(const void* __restrict__ in,
                                                u16* __restrict__ out,
                                                int n4, const int* __restrict__ flag)
{
  const int i = blockIdx.x * 256 + threadIdx.x;
  if (i >= n4) return;
  if (*flag) {
    const float4 v = ((const float4*)in)[i];
    u16 o0 = f2bf(v.x), o1 = f2bf(v.y), o2 = f2bf(v.z), o3 = f2bf(v.w);
    uint2 p; p.x = (unsigned)o0 | ((unsigned)o1 << 16); p.y = (unsigned)o2 | ((unsigned)o3 << 16);
    ((uint2*)out)[i] = p;
  } else {
    ((uint2*)out)[i] = ((const uint2*)in)[i];
  }
}

// ---------------- cast+transpose: in [R,C] (flag? f32 : bf16) -> bf16 [C,R] ----------------
__global__ __launch_bounds__(256) void ct_transpose_k(const void* __restrict__ in,
                                                      u16* __restrict__ out,
                                                      int R, int C, const int* __restrict__ flag)
{
  __shared__ u16 tile[32][33];
  const int f = *flag;
  const int c0 = blockIdx.x * 32, r0 = blockIdx.y * 32;
  const int tx = threadIdx.x & 31, ty = threadIdx.x >> 5;
#pragma unroll
  for (int i = ty; i < 32; i += 8) {
    const size_t idx = (size_t)(r0 + i) * C + (c0 + tx);
    tile[i][tx] = f ? f2bf(((const float*)in)[idx]) : ((const u16*)in)[idx];
  }
  __syncthreads();
#pragma unroll
  for (int i = ty; i < 32; i += 8)
    out[(size_t)(c0 + i) * R + (r0 + tx)] = tile[tx][i];
}

// ---------------- bias -> fp32 ----------------
__global__ __launch_bounds__(256) void bias_cast_k(const void* __restrict__ in,
                                                   float* __restrict__ out,
                                                   int n, const int* __restrict__ flag)
{
  const int i = blockIdx.x * 256 + threadIdx.x;
  if (i >= n) return;
  out[i] = *flag ? ((const float*)in)[i] : bf2f(((const u16*)in)[i]);
}

// ---------------- GEMM C[M,N] = A[M,K] @ Bt[N,K]^T (+bias), bf16 MFMA ----------------
// m97 structure: 128x128 tile, 4 waves, 16x16x32 MFMA, BK=32, global_load_lds x16B
__global__ __launch_bounds__(256) void gemm_bt(
    const u16* __restrict__ A, const u16* __restrict__ Bt,
    const float* __restrict__ bias, void* __restrict__ C,
    int M, int N, int K, const int* __restrict__ flag, int flagOut)
{
  __shared__ u16 As[128 * 32];
  __shared__ u16 Bs[128 * 32];
  const int t = threadIdx.x;
  const int wave = t >> 6, lane = t & 63;
  const int quad = lane >> 4, l15 = lane & 15;
  const int wr = (wave >> 1) << 6, wc = (wave & 1) << 6;
  const size_t m0 = (size_t)blockIdx.x * 128;
  const size_t n0 = (size_t)blockIdx.y * 128;

  const u16* ag0 = A + (m0 + (t >> 2)) * (size_t)K + (t & 3) * 8;
  const u16* ag1 = ag0 + (size_t)64 * K;
  const u16* bg0 = Bt + (n0 + (t >> 2)) * (size_t)K + (t & 3) * 8;
  const u16* bg1 = bg0 + (size_t)64 * K;
  u16* la = As + wave * 512;   // HW adds lane*16B
  u16* lb = Bs + wave * 512;

  floatx4 acc[4][4] = {};

  for (int k0 = 0; k0 < K; k0 += 32) {
    glds16(ag0 + k0, la);
    glds16(ag1 + k0, la + 2048);
    glds16(bg0 + k0, lb);
    glds16(bg1 + k0, lb + 2048);
    __syncthreads();
    bf16x8 af[4], bfv[4];
#pragma unroll
    for (int i = 0; i < 4; ++i)
      af[i] = *(const bf16x8*)(As + (wr + i * 16 + l15) * 32 + quad * 8);
#pragma unroll
    for (int j = 0; j < 4; ++j)
      bfv[j] = *(const bf16x8*)(Bs + (wc + j * 16 + l15) * 32 + quad * 8);
#pragma unroll
    for (int i = 0; i < 4; ++i)
#pragma unroll
      for (int j = 0; j < 4; ++j)
        acc[i][j] = __builtin_amdgcn_mfma_f32_16x16x32_bf16(af[i], bfv[j], acc[i][j], 0, 0, 0);
    __syncthreads();
  }

  const int f32out = flagOut && (*flag);
#pragma unroll
  for (int j = 0; j < 4; ++j) {
    const size_t col = n0 + wc + j * 16 + l15;
    const float bv = bias ? bias[col] : 0.0f;
#pragma unroll
    for (int i = 0; i < 4; ++i) {
      const size_t row = m0 + wr + i * 16 + quad * 4;
#pragma unroll
      for (int r = 0; r < 4; ++r) {
        const float v = acc[i][j][r] + bv;
        if (f32out) ((float*)C)[(row + r) * (size_t)N + col] = v;
        else        ((u16*)C)[(row + r) * (size_t)N + col] = f2bf(v);
      }
    }
  }
}

// ---------------- windowed attention ----------------
// one block (4 waves) per (b, l, head); N_=196 padded to 208 (S cols) / 224 (PV K)
#define NP 232  // padded LDS stride (bf16 elems)

__global__ __launch_bounds__(256) void attn_win(
    const u16* __restrict__ qkv, u16* __restrict__ o)
{
  __shared__ u16 Vt[64 * NP];       // Vt[d][k], k<224 (>=196 zero)
  __shared__ u16 Pb[4][16 * NP];    // per-wave P strip [16 rows][<=224 cols]

  const int bid = blockIdx.x;
  const int h = bid % 12;
  const int l = (bid / 12) % 16;
  const int b = bid / 192;
  const int wr0 = (l >> 2) * 14, wc0 = (l & 3) * 14;
  const int baseTok = b * 3136;

  const int t = threadIdx.x, wave = t >> 6, lane = t & 63;
  const int quad = lane >> 4, l15 = lane & 15;

  // stage V transposed: Vt[d][n] = V[n][d]
  for (int idx = t; idx < 224 * 64; idx += 256) {
    const int n = idx >> 6, d = idx & 63;
    u16 v = 0;
    if (n < 196) {
      const int g = baseTok + (wr0 + n / 14) * 56 + wc0 + n % 14;
      v = qkv[(size_t)g * 2304 + 1536 + h * 64 + d];
    }
    Vt[d * NP + n] = v;
  }
  __syncthreads();

  u16* Pw = &Pb[wave][0];

  for (int rt = wave; rt < 13; rt += 4) {
    const int n0 = rt * 16;
    // Q fragments (A-layout: row = l15, k = quad*8+j)
    int qn = n0 + l15; if (qn > 195) qn = 195;
    const int gq = baseTok + (wr0 + qn / 14) * 56 + wc0 + qn % 14;
    const u16* qrow = qkv + (size_t)gq * 2304 + h * 64 + quad * 8;
    const bf16x8 aq0 = *(const bf16x8*)(qrow);
    const bf16x8 aq1 = *(const bf16x8*)(qrow + 32);

    floatx4 s[13];
#pragma unroll
    for (int ct = 0; ct < 13; ++ct) {
      int kn = ct * 16 + l15; if (kn > 195) kn = 195;
      const int gk = baseTok + (wr0 + kn / 14) * 56 + wc0 + kn % 14;
      const u16* krow = qkv + (size_t)gk * 2304 + 768 + h * 64 + quad * 8;
      const bf16x8 bk0 = *(const bf16x8*)(krow);
      const bf16x8 bk1 = *(const bf16x8*)(krow + 32);
      floatx4 z = {};
      z = __builtin_amdgcn_mfma_f32_16x16x32_bf16(aq0, bk0, z, 0, 0, 0);
      z = __builtin_amdgcn_mfma_f32_16x16x32_bf16(aq1, bk1, z, 0, 0, 0);
      s[ct] = z;
    }

    // softmax across cols (col = ct*16 + l15); rows = n0 + quad*4 + r
    float mx[4], sm[4];
#pragma unroll
    for (int r = 0; r < 4; ++r) mx[r] = -3e38f;
#pragma unroll
    for (int ct = 0; ct < 13; ++ct) {
      const bool maskct = (ct == 12) && (l15 >= 4);
#pragma unroll
      for (int r = 0; r < 4; ++r) {
        float v = s[ct][r] * 0.125f;   // scale = 1/sqrt(64)
        if (maskct) v = -3e38f;
        s[ct][r] = v;
        mx[r] = fmaxf(mx[r], v);
      }
    }
#pragma unroll
    for (int r = 0; r < 4; ++r)
      for (int off = 1; off < 16; off <<= 1)
        mx[r] = fmaxf(mx[r], __shfl_xor(mx[r], off, 64));
#pragma unroll
    for (int r = 0; r < 4; ++r) sm[r] = 0.0f;
#pragma unroll
    for (int ct = 0; ct < 13; ++ct)
#pragma unroll
      for (int r = 0; r < 4; ++r) {
        const float p = __expf(s[ct][r] - mx[r]);
        s[ct][r] = p;
        sm[r] += p;
      }
#pragma unroll
    for (int r = 0; r < 4; ++r)
      for (int off = 1; off < 16; off <<= 1)
        sm[r] += __shfl_xor(sm[r], off, 64);

    // P -> LDS (A-operand layout round-trip)
#pragma unroll
    for (int ct = 0; ct < 13; ++ct)
#pragma unroll
      for (int r = 0; r < 4; ++r)
        Pw[(quad * 4 + r) * NP + ct * 16 + l15] = f2bf(s[ct][r]);
#pragma unroll
    for (int r = 0; r < 4; ++r)
      Pw[(quad * 4 + r) * NP + 208 + l15] = 0;  // zero pad cols 208..223

    // O = P @ V  (K = 224 in 7 steps)
    floatx4 oacc[4] = {};
#pragma unroll
    for (int ks = 0; ks < 7; ++ks) {
      const bf16x8 ap = *(const bf16x8*)(Pw + l15 * NP + ks * 32 + quad * 8);
#pragma unroll
      for (int nt = 0; nt < 4; ++nt) {
        const bf16x8 bv = *(const bf16x8*)(Vt + (nt * 16 + l15) * NP + ks * 32 + quad * 8);
        oacc[nt] = __builtin_amdgcn_mfma_f32_16x16x32_bf16(ap, bv, oacc[nt], 0, 0, 0);
      }
    }

    float rs[4];
#pragma unroll
    for (int r = 0; r < 4; ++r) rs[r] = 1.0f / sm[r];

#pragma unroll
    for (int r = 0; r < 4; ++r) {
      const int n = n0 + quad * 4 + r;
      if (n < 196) {
        const int g = baseTok + (wr0 + n / 14) * 56 + wc0 + n % 14;
#pragma unroll
        for (int nt = 0; nt < 4; ++nt)
          o[(size_t)g * 768 + h * 64 + nt * 16 + l15] = f2bf(oacc[nt][r] * rs[r]);
      }
    }
  }
}

extern "C" void kernel_launch(void* const* d_in, const int* in_sizes, int n_in,
                              void* d_out, int out_size, void* d_ws, size_t ws_size,
                              hipStream_t stream)
{
  const void* x     = d_in[0];  // [8,3136,768]   fp32 or bf16
  const void* wqkv  = d_in[1];  // [768,2304]
  const void* wproj = d_in[2];  // [768,768]
  const void* bproj = d_in[3];  // [768]

  char* ws = (char*)d_ws;
  int*   flag   = (int*)ws;                         // 16 B
  float* bprojF = (float*)(ws + 16);                // 768 f32 -> ends 3088
  u16*   wqkvT  = (u16*)(ws + 4096);                // 2304*768 bf16 -> ends 3543040
  u16*   wprojT = (u16*)(ws + 3543040);             // 768*768  bf16 -> ends 4722688
  u16*   qkvbuf = (u16*)(ws + 4722688);             // 25088*2304 bf16 -> ends 120328192
  u16*   xb     = (u16*)(ws + 120328192);           // 25088*768 bf16 (reused as attn out)
  u16*   attno  = xb;

  detect_k<<<1, 256, 0, stream>>>((const u16*)wqkv, flag);
  cast_x_k<<<dim3(18816), 256, 0, stream>>>(x, xb, 4816896, flag);
  ct_transpose_k<<<dim3(72, 24), 256, 0, stream>>>(wqkv, wqkvT, 768, 2304, flag);
  ct_transpose_k<<<dim3(24, 24), 256, 0, stream>>>(wproj, wprojT, 768, 768, flag);
  bias_cast_k<<<dim3(3), 256, 0, stream>>>(bproj, bprojF, 768, flag);

  gemm_bt<<<dim3(196, 18), 256, 0, stream>>>(xb, wqkvT, (const float*)nullptr, qkvbuf,
                                             25088, 2304, 768, flag, 0);
  attn_win<<<dim3(1536), 256, 0, stream>>>(qkvbuf, attno);
  gemm_bt<<<dim3(196, 6), 256, 0, stream>>>(attno, wprojT, bprojF, d_out,
                                            25088, 768, 768, flag, 1);
}

// Round 4
// 443.814 us; speedup vs baseline: 1.1184x; 1.1184x over previous
//
#include <hip/hip_runtime.h>

typedef unsigned short u16;
typedef __attribute__((ext_vector_type(8))) __bf16 bf16x8;
typedef __attribute__((ext_vector_type(4))) float floatx4;

__device__ inline float bf2f(u16 u) {
  union { unsigned u; float f; } v; v.u = ((unsigned)u) << 16; return v.f;
}
__device__ inline u16 f2bf(float f) {
  union { float f; unsigned u; } v; v.f = f;
  unsigned r = v.u + 0x7fffu + ((v.u >> 16) & 1u);
  return (u16)(r >> 16);
}

__device__ inline void glds16(const u16* g, u16* l) {
  __builtin_amdgcn_global_load_lds((const __attribute__((address_space(1))) void*)g,
                                   (__attribute__((address_space(3))) void*)l, 16, 0, 0);
}

// ---------------- dtype probe: fp32-as-u16 halves have wild exponents ----------------
__global__ __launch_bounds__(256) void detect_k(const u16* __restrict__ w, int* flag)
{
  __shared__ int cnt;
  if (threadIdx.x == 0) cnt = 0;
  __syncthreads();
  int c = 0;
  for (int i = threadIdx.x; i < 16384; i += 256) {
    const int e = (w[i] >> 7) & 0xFF;
    if (e < 64 || e > 191) ++c;
  }
  atomicAdd(&cnt, c);
  __syncthreads();
  if (threadIdx.x == 0) *flag = (cnt > 256) ? 1 : 0;   // 1 => inputs are fp32
}

// ---------------- x -> bf16 (copy or downcast), 4 elems/thread ----------------
__global__ __launch_bounds__(256) void cast_x_k(const void* __restrict__ in,
                                                u16* __restrict__ out,
                                                int n4, const int* __restrict__ flag)
{
  const int i = blockIdx.x * 256 + threadIdx.x;
  if (i >= n4) return;
  if (*flag) {
    const float4 v = ((const float4*)in)[i];
    u16 o0 = f2bf(v.x), o1 = f2bf(v.y), o2 = f2bf(v.z), o3 = f2bf(v.w);
    uint2 p; p.x = (unsigned)o0 | ((unsigned)o1 << 16); p.y = (unsigned)o2 | ((unsigned)o3 << 16);
    ((uint2*)out)[i] = p;
  } else {
    ((uint2*)out)[i] = ((const uint2*)in)[i];
  }
}

// ---------------- cast+transpose: in [R,C] (flag? f32 : bf16) -> bf16 [C,R] ----------------
__global__ __launch_bounds__(256) void ct_transpose_k(const void* __restrict__ in,
                                                      u16* __restrict__ out,
                                                      int R, int C, const int* __restrict__ flag)
{
  __shared__ u16 tile[32][33];
  const int f = *flag;
  const int c0 = blockIdx.x * 32, r0 = blockIdx.y * 32;
  const int tx = threadIdx.x & 31, ty = threadIdx.x >> 5;
#pragma unroll
  for (int i = ty; i < 32; i += 8) {
    const size_t idx = (size_t)(r0 + i) * C + (c0 + tx);
    tile[i][tx] = f ? f2bf(((const float*)in)[idx]) : ((const u16*)in)[idx];
  }
  __syncthreads();
#pragma unroll
  for (int i = ty; i < 32; i += 8)
    out[(size_t)(c0 + i) * R + (r0 + tx)] = tile[tx][i];
}

// ---------------- bias -> fp32 ----------------
__global__ __launch_bounds__(256) void bias_cast_k(const void* __restrict__ in,
                                                   float* __restrict__ out,
                                                   int n, const int* __restrict__ flag)
{
  const int i = blockIdx.x * 256 + threadIdx.x;
  if (i >= n) return;
  out[i] = *flag ? ((const float*)in)[i] : bf2f(((const u16*)in)[i]);
}

// ---------------- GEMM C[M,N] = A[M,K] @ Bt[N,K]^T (+bias), bf16 MFMA ----------------
// 128x128 tile, 4 waves, 16x16x32 MFMA, BK=32, glds x16, XOR-swizzled LDS,
// coalesced epilogue via per-wave LDS repack.
__global__ __launch_bounds__(256) void gemm_bt(
    const u16* __restrict__ A, const u16* __restrict__ Bt,
    const float* __restrict__ bias, void* __restrict__ C,
    int M, int N, int K, const int* __restrict__ flag, int flagOut)
{
  __shared__ u16 smem[8192];          // As[0..4095], Bs[4096..8191]
  u16* As = smem;
  u16* Bs = smem + 4096;
  const int t = threadIdx.x;
  const int wave = t >> 6, lane = t & 63;
  const int quad = lane >> 4, l15 = lane & 15;
  const int wr = (wave >> 1) << 6, wc = (wave & 1) << 6;
  const size_t m0 = (size_t)blockIdx.x * 128;
  const size_t n0 = (size_t)blockIdx.y * 128;

  // staging: thread t owns LDS slot (row = t>>2, c = t&3); load global k-group c ^ key(row)
  const int sgk = (((t & 3) ^ ((t >> 3) & 3))) * 8;
  const u16* ag0 = A + (m0 + (t >> 2)) * (size_t)K + sgk;
  const u16* ag1 = ag0 + (size_t)64 * K;
  const u16* bg0 = Bt + (n0 + (t >> 2)) * (size_t)K + sgk;
  const u16* bg1 = bg0 + (size_t)64 * K;
  u16* la = As + wave * 512;   // HW adds lane*16B
  u16* lb = Bs + wave * 512;

  const int kx = (l15 >> 1) & 3;           // read-side XOR key
  const int xq = (quad ^ kx) * 8;

  floatx4 acc[4][4] = {};

  for (int k0 = 0; k0 < K; k0 += 32) {
    glds16(ag0 + k0, la);
    glds16(ag1 + k0, la + 2048);
    glds16(bg0 + k0, lb);
    glds16(bg1 + k0, lb + 2048);
    __syncthreads();
    bf16x8 af[4], bfv[4];
#pragma unroll
    for (int i = 0; i < 4; ++i)
      af[i] = *(const bf16x8*)(As + (wr + i * 16 + l15) * 32 + xq);
#pragma unroll
    for (int j = 0; j < 4; ++j)
      bfv[j] = *(const bf16x8*)(Bs + (wc + j * 16 + l15) * 32 + xq);
#pragma unroll
    for (int i = 0; i < 4; ++i)
#pragma unroll
      for (int j = 0; j < 4; ++j)
        acc[i][j] = __builtin_amdgcn_mfma_f32_16x16x32_bf16(af[i], bfv[j], acc[i][j], 0, 0, 0);
    __syncthreads();
  }

  // -------- epilogue: per-wave LDS repack -> coalesced 16B stores --------
  float bvj[4];
#pragma unroll
  for (int j = 0; j < 4; ++j)
    bvj[j] = bias ? bias[n0 + wc + j * 16 + l15] : 0.0f;

  if (flagOut && (*flag)) {
    // fp32 output: 16 rows x 32 cols per pass (stride 36 f32)
    float* scrf = (float*)smem + wave * 576;
    float* Cf = (float*)C;
#pragma unroll
    for (int i = 0; i < 4; ++i)
#pragma unroll
      for (int jp = 0; jp < 2; ++jp) {
#pragma unroll
        for (int jj = 0; jj < 2; ++jj)
#pragma unroll
          for (int r = 0; r < 4; ++r)
            scrf[(quad * 4 + r) * 36 + jj * 16 + l15] = acc[i][jp * 2 + jj][r] + bvj[jp * 2 + jj];
#pragma unroll
        for (int u = lane; u < 128; u += 64) {
          const int row = u >> 3, gr = u & 7;
          float4 vv = *(const float4*)(scrf + row * 36 + gr * 4);
          *(float4*)(Cf + (m0 + wr + i * 16 + row) * (size_t)N + n0 + wc + jp * 32 + gr * 4) = vv;
        }
      }
  } else {
    // bf16 output: 16 rows x 64 cols per pass (stride 72 u16)
    u16* scr = smem + wave * 1152;
    u16* Cb = (u16*)C;
#pragma unroll
    for (int i = 0; i < 4; ++i) {
#pragma unroll
      for (int j = 0; j < 4; ++j)
#pragma unroll
        for (int r = 0; r < 4; ++r)
          scr[(quad * 4 + r) * 72 + j * 16 + l15] = f2bf(acc[i][j][r] + bvj[j]);
#pragma unroll
      for (int u = lane; u < 128; u += 64) {
        const int row = u >> 3, gr = u & 7;
        int4 vv = *(const int4*)(scr + row * 72 + gr * 8);
        *(int4*)(Cb + (m0 + wr + i * 16 + row) * (size_t)N + n0 + wc + gr * 8) = vv;
      }
    }
  }
}

// ---------------- windowed attention ----------------
// one block (4 waves) per (b, l, head). K staged in LDS (XOR-64), V^T and P at
// stride 208 (2-way banks = free). LDS total 79.2 KB -> 2 blocks/CU.
__global__ __launch_bounds__(256, 2) void attn_win(
    const u16* __restrict__ qkv, u16* __restrict__ o)
{
  __shared__ u16 Ks[196 * 64];      // slot16B = row*8 + (g ^ (row&7))
  __shared__ u16 Vt[64 * 208];      // Vt[d][n], cols >=196 zero
  __shared__ u16 Pb[4][16 * 208];   // per-wave strip
  __shared__ int gtok[208];

  const int bid = blockIdx.x;
  const int h = bid % 12;
  const int l = (bid / 12) % 16;
  const int b = bid / 192;
  const int wr0 = (l >> 2) * 14, wc0 = (l & 3) * 14;
  const int baseTok = b * 3136;

  const int t = threadIdx.x, wave = t >> 6, lane = t & 63;
  const int quad = lane >> 4, l15 = lane & 15;

  if (t < 208) {
    const int nn = t < 196 ? t : 195;
    gtok[t] = baseTok + (wr0 + nn / 14) * 56 + wc0 + nn % 14;
  }
  __syncthreads();

  // stage K (rows 0..195, 8 d-groups, XOR layout)
  for (int u = t; u < 196 * 8; u += 256) {
    const int row = u >> 3, gg = u & 7;
    int4 kv = *(const int4*)(qkv + (size_t)gtok[row] * 2304 + 768 + h * 64 + gg * 8);
    *(int4*)(Ks + (row * 8 + (gg ^ (row & 7))) * 8) = kv;
  }
  // stage V transposed: Vt[d][n]
  for (int u = t; u < 208 * 8; u += 256) {
    const int n = u >> 3, dg = u & 7;
    int4 vv = {0, 0, 0, 0};
    if (n < 196)
      vv = *(const int4*)(qkv + (size_t)gtok[n] * 2304 + 1536 + h * 64 + dg * 8);
    const u16* pv = (const u16*)&vv;
#pragma unroll
    for (int j = 0; j < 8; ++j) Vt[(dg * 8 + j) * 208 + n] = pv[j];
  }
  __syncthreads();

  u16* Pw = &Pb[wave][0];
  const bf16x8 zerov = {};

  for (int rt = wave; rt < 13; rt += 4) {
    const int n0r = rt * 16;
    int qn = n0r + l15; if (qn > 195) qn = 195;
    const u16* qrow = qkv + (size_t)gtok[qn] * 2304 + h * 64;
    const bf16x8 aq0 = *(const bf16x8*)(qrow + quad * 8);
    const bf16x8 aq1 = *(const bf16x8*)(qrow + 32 + quad * 8);

    floatx4 s[13];
#pragma unroll
    for (int ct = 0; ct < 13; ++ct) {
      int kr = ct * 16 + l15; if (kr > 195) kr = 195;
      const bf16x8 bk0 = *(const bf16x8*)(Ks + (kr * 8 + (quad ^ (kr & 7))) * 8);
      const bf16x8 bk1 = *(const bf16x8*)(Ks + (kr * 8 + ((quad + 4) ^ (kr & 7))) * 8);
      floatx4 z = {};
      z = __builtin_amdgcn_mfma_f32_16x16x32_bf16(aq0, bk0, z, 0, 0, 0);
      z = __builtin_amdgcn_mfma_f32_16x16x32_bf16(aq1, bk1, z, 0, 0, 0);
      s[ct] = z;
    }

    // softmax: col = ct*16+l15, rows = n0r + quad*4 + r
    float mx[4], sm[4];
#pragma unroll
    for (int r = 0; r < 4; ++r) mx[r] = -3e38f;
#pragma unroll
    for (int ct = 0; ct < 13; ++ct) {
      const bool maskct = (ct == 12) && (l15 >= 4);
#pragma unroll
      for (int r = 0; r < 4; ++r) {
        float v = s[ct][r] * 0.125f;
        if (maskct) v = -3e38f;
        s[ct][r] = v;
        mx[r] = fmaxf(mx[r], v);
      }
    }
#pragma unroll
    for (int r = 0; r < 4; ++r)
      for (int off = 1; off < 16; off <<= 1)
        mx[r] = fmaxf(mx[r], __shfl_xor(mx[r], off, 64));
#pragma unroll
    for (int r = 0; r < 4; ++r) sm[r] = 0.0f;
#pragma unroll
    for (int ct = 0; ct < 13; ++ct)
#pragma unroll
      for (int r = 0; r < 4; ++r) {
        const float p = __expf(s[ct][r] - mx[r]);
        s[ct][r] = p;
        sm[r] += p;
      }
#pragma unroll
    for (int r = 0; r < 4; ++r)
      for (int off = 1; off < 16; off <<= 1)
        sm[r] += __shfl_xor(sm[r], off, 64);

    // P -> LDS (A-layout round trip); cols 0..207 fully covered
#pragma unroll
    for (int ct = 0; ct < 13; ++ct)
#pragma unroll
      for (int r = 0; r < 4; ++r)
        Pw[(quad * 4 + r) * 208 + ct * 16 + l15] = f2bf(s[ct][r]);

    // O = P @ V: 6 full K=32 steps + masked tail (k 192..207 real)
    floatx4 oacc[4] = {};
#pragma unroll
    for (int ks = 0; ks < 6; ++ks) {
      const bf16x8 ap = *(const bf16x8*)(Pw + l15 * 208 + ks * 32 + quad * 8);
#pragma unroll
      for (int nt = 0; nt < 4; ++nt) {
        const bf16x8 bv = *(const bf16x8*)(Vt + (nt * 16 + l15) * 208 + ks * 32 + quad * 8);
        oacc[nt] = __builtin_amdgcn_mfma_f32_16x16x32_bf16(ap, bv, oacc[nt], 0, 0, 0);
      }
    }
    {
      const int off = 192 + (quad & 1) * 8;
      bf16x8 ap = *(const bf16x8*)(Pw + l15 * 208 + off);
      if (quad >= 2) ap = zerov;
#pragma unroll
      for (int nt = 0; nt < 4; ++nt) {
        const bf16x8 bv = *(const bf16x8*)(Vt + (nt * 16 + l15) * 208 + off);
        oacc[nt] = __builtin_amdgcn_mfma_f32_16x16x32_bf16(ap, bv, oacc[nt], 0, 0, 0);
      }
    }

    float rs[4];
#pragma unroll
    for (int r = 0; r < 4; ++r) rs[r] = 1.0f / sm[r];

    // O -> Pw repack -> coalesced 16B stores
#pragma unroll
    for (int nt = 0; nt < 4; ++nt)
#pragma unroll
      for (int r = 0; r < 4; ++r)
        Pw[(quad * 4 + r) * 208 + nt * 16 + l15] = f2bf(oacc[nt][r] * rs[r]);
#pragma unroll
    for (int u = lane; u < 128; u += 64) {
      const int row = u >> 3, gr = u & 7;
      const int n = n0r + row;
      if (n < 196) {
        int4 vv = *(const int4*)(Pw + row * 208 + gr * 8);
        *(int4*)(o + (size_t)gtok[n] * 768 + h * 64 + gr * 8) = vv;
      }
    }
  }
}

extern "C" void kernel_launch(void* const* d_in, const int* in_sizes, int n_in,
                              void* d_out, int out_size, void* d_ws, size_t ws_size,
                              hipStream_t stream)
{
  const void* x     = d_in[0];  // [8,3136,768]   fp32 or bf16
  const void* wqkv  = d_in[1];  // [768,2304]
  const void* wproj = d_in[2];  // [768,768]
  const void* bproj = d_in[3];  // [768]

  char* ws = (char*)d_ws;
  int*   flag   = (int*)ws;                         // 16 B
  float* bprojF = (float*)(ws + 16);                // 768 f32
  u16*   wqkvT  = (u16*)(ws + 4096);                // 2304*768 bf16
  u16*   wprojT = (u16*)(ws + 3543040);             // 768*768  bf16
  u16*   qkvbuf = (u16*)(ws + 4722688);             // 25088*2304 bf16
  u16*   xb     = (u16*)(ws + 120328192);           // 25088*768 bf16 (reused as attn out)
  u16*   attno  = xb;

  detect_k<<<1, 256, 0, stream>>>((const u16*)wqkv, flag);
  cast_x_k<<<dim3(18816), 256, 0, stream>>>(x, xb, 4816896, flag);
  ct_transpose_k<<<dim3(72, 24), 256, 0, stream>>>(wqkv, wqkvT, 768, 2304, flag);
  ct_transpose_k<<<dim3(24, 24), 256, 0, stream>>>(wproj, wprojT, 768, 768, flag);
  bias_cast_k<<<dim3(3), 256, 0, stream>>>(bproj, bprojF, 768, flag);

  gemm_bt<<<dim3(196, 18), 256, 0, stream>>>(xb, wqkvT, (const float*)nullptr, qkvbuf,
                                             25088, 2304, 768, flag, 0);
  attn_win<<<dim3(1536), 256, 0, stream>>>(qkvbuf, attno);
  gemm_bt<<<dim3(196, 6), 256, 0, stream>>>(attno, wprojT, bprojF, d_out,
                                            25088, 768, 768, flag, 1);
}

// Round 5
// 402.581 us; speedup vs baseline: 1.2329x; 1.1024x over previous
//
#include <hip/hip_runtime.h>

typedef unsigned short u16;
typedef __attribute__((ext_vector_type(8))) __bf16 bf16x8;
typedef __attribute__((ext_vector_type(4))) float floatx4;

__device__ inline float bf2f(u16 u) {
  union { unsigned u; float f; } v; v.u = ((unsigned)u) << 16; return v.f;
}
__device__ inline u16 f2bf(float f) {
  union { float f; unsigned u; } v; v.f = f;
  unsigned r = v.u + 0x7fffu + ((v.u >> 16) & 1u);
  return (u16)(r >> 16);
}

__device__ inline void glds16(const u16* g, u16* l) {
  __builtin_amdgcn_global_load_lds((const __attribute__((address_space(1))) void*)g,
                                   (__attribute__((address_space(3))) void*)l, 16, 0, 0);
}

// ---------------- dtype probe: fp32-as-u16 halves have wild exponents ----------------
__global__ __launch_bounds__(256) void detect_k(const u16* __restrict__ w, int* flag)
{
  __shared__ int cnt;
  if (threadIdx.x == 0) cnt = 0;
  __syncthreads();
  int c = 0;
  for (int i = threadIdx.x; i < 16384; i += 256) {
    const int e = (w[i] >> 7) & 0xFF;
    if (e < 64 || e > 191) ++c;
  }
  atomicAdd(&cnt, c);
  __syncthreads();
  if (threadIdx.x == 0) *flag = (cnt > 256) ? 1 : 0;   // 1 => inputs are fp32
}

// ---------------- x -> bf16 (copy or downcast), 4 elems/thread ----------------
__global__ __launch_bounds__(256) void cast_x_k(const void* __restrict__ in,
                                                u16* __restrict__ out,
                                                int n4, const int* __restrict__ flag)
{
  const int i = blockIdx.x * 256 + threadIdx.x;
  if (i >= n4) return;
  if (*flag) {
    const float4 v = ((const float4*)in)[i];
    u16 o0 = f2bf(v.x), o1 = f2bf(v.y), o2 = f2bf(v.z), o3 = f2bf(v.w);
    uint2 p; p.x = (unsigned)o0 | ((unsigned)o1 << 16); p.y = (unsigned)o2 | ((unsigned)o3 << 16);
    ((uint2*)out)[i] = p;
  } else {
    ((uint2*)out)[i] = ((const uint2*)in)[i];
  }
}

// ---------------- cast+transpose: in [R,C] (flag? f32 : bf16) -> bf16 [C,R] ----------------
__global__ __launch_bounds__(256) void ct_transpose_k(const void* __restrict__ in,
                                                      u16* __restrict__ out,
                                                      int R, int C, const int* __restrict__ flag)
{
  __shared__ u16 tile[32][33];
  const int f = *flag;
  const int c0 = blockIdx.x * 32, r0 = blockIdx.y * 32;
  const int tx = threadIdx.x & 31, ty = threadIdx.x >> 5;
#pragma unroll
  for (int i = ty; i < 32; i += 8) {
    const size_t idx = (size_t)(r0 + i) * C + (c0 + tx);
    tile[i][tx] = f ? f2bf(((const float*)in)[idx]) : ((const u16*)in)[idx];
  }
  __syncthreads();
#pragma unroll
  for (int i = ty; i < 32; i += 8)
    out[(size_t)(c0 + i) * R + (r0 + tx)] = tile[tx][i];
}

// ---------------- bias -> fp32 ----------------
__global__ __launch_bounds__(256) void bias_cast_k(const void* __restrict__ in,
                                                   float* __restrict__ out,
                                                   int n, const int* __restrict__ flag)
{
  const int i = blockIdx.x * 256 + threadIdx.x;
  if (i >= n) return;
  out[i] = *flag ? ((const float*)in)[i] : bf2f(((const u16*)in)[i]);
}

// ---------------- GEMM C[M,N] = A[M,K] @ Bt[N,K]^T (+bias), bf16 MFMA ----------------
// 128x128 tile, 4 waves, 16x16x32 MFMA, BK=64 (half the barrier drains of BK=32),
// XOR-swizzled LDS (16B slot = g ^ (row&7)), L2-friendly 14x14 super-group remap,
// coalesced epilogue via per-wave LDS repack.
__global__ __launch_bounds__(256) void gemm_bt(
    const u16* __restrict__ A, const u16* __restrict__ Bt,
    const float* __restrict__ bias, void* __restrict__ C,
    int M, int N, int K, const int* __restrict__ flag, int flagOut, int NT)
{
  __shared__ u16 smem[16384];          // As[0..8191], Bs[8192..16383]  (32 KB)
  u16* As = smem;
  u16* Bs = smem + 8192;
  const int t = threadIdx.x;
  const int wave = t >> 6, lane = t & 63;
  const int quad = lane >> 4, l15 = lane & 15;
  const int wr = (wave >> 1) << 6, wc = (wave & 1) << 6;

  // block remap: super-groups of 14 M-tiles x NT N-tiles (196 = 14*14)
  const int id = blockIdx.x;
  const int grp = id / (14 * NT), rem = id % (14 * NT);
  const int mt = grp * 14 + rem % 14;
  const int ntile = rem / 14;
  const size_t m0 = (size_t)mt * 128;
  const size_t n0 = (size_t)ntile * 128;

  // staging: thread t owns 4 A-slots + 4 B-slots; slot s = w*256 + wave*64 + lane
  // -> row = w*32 + wave*8 + (lane>>3), stored group gs = lane&7,
  //    global k-group = gs ^ (row&7) = (lane&7) ^ (lane>>3)
  const int srow = wave * 8 + (lane >> 3);
  const int sg = ((lane & 7) ^ (lane >> 3)) * 8;
  const u16* ag = A + (m0 + srow) * (size_t)K + sg;
  const u16* bg = Bt + (n0 + srow) * (size_t)K + sg;
  u16* la = As + wave * 512;   // HW adds lane*16B
  u16* lb = Bs + wave * 512;

  floatx4 acc[4][4] = {};

  for (int k0 = 0; k0 < K; k0 += 64) {
#pragma unroll
    for (int w = 0; w < 4; ++w) glds16(ag + k0 + (size_t)(w * 32) * K, la + w * 2048);
#pragma unroll
    for (int w = 0; w < 4; ++w) glds16(bg + k0 + (size_t)(w * 32) * K, lb + w * 2048);
    __syncthreads();
#pragma unroll
    for (int ks = 0; ks < 2; ++ks) {
      bf16x8 af[4], bfv[4];
      const int gf = ks * 4 + quad;
      const int slot = (gf ^ (l15 & 7)) * 8;
#pragma unroll
      for (int i = 0; i < 4; ++i)
        af[i] = *(const bf16x8*)(As + (wr + i * 16 + l15) * 64 + slot);
#pragma unroll
      for (int j = 0; j < 4; ++j)
        bfv[j] = *(const bf16x8*)(Bs + (wc + j * 16 + l15) * 64 + slot);
#pragma unroll
      for (int i = 0; i < 4; ++i)
#pragma unroll
        for (int j = 0; j < 4; ++j)
          acc[i][j] = __builtin_amdgcn_mfma_f32_16x16x32_bf16(af[i], bfv[j], acc[i][j], 0, 0, 0);
    }
    __syncthreads();
  }

  // -------- epilogue: per-wave LDS repack -> coalesced 16B stores --------
  float bvj[4];
#pragma unroll
  for (int j = 0; j < 4; ++j)
    bvj[j] = bias ? bias[n0 + wc + j * 16 + l15] : 0.0f;

  if (flagOut && (*flag)) {
    // fp32 output: 16 rows x 32 cols per pass (stride 36 f32)
    float* scrf = (float*)smem + wave * 576;
    float* Cf = (float*)C;
#pragma unroll
    for (int i = 0; i < 4; ++i)
#pragma unroll
      for (int jp = 0; jp < 2; ++jp) {
#pragma unroll
        for (int jj = 0; jj < 2; ++jj)
#pragma unroll
          for (int r = 0; r < 4; ++r)
            scrf[(quad * 4 + r) * 36 + jj * 16 + l15] = acc[i][jp * 2 + jj][r] + bvj[jp * 2 + jj];
#pragma unroll
        for (int u = lane; u < 128; u += 64) {
          const int row = u >> 3, gr = u & 7;
          float4 vv = *(const float4*)(scrf + row * 36 + gr * 4);
          *(float4*)(Cf + (m0 + wr + i * 16 + row) * (size_t)N + n0 + wc + jp * 32 + gr * 4) = vv;
        }
      }
  } else {
    // bf16 output: 16 rows x 64 cols per pass (stride 72 u16)
    u16* scr = smem + wave * 1152;
    u16* Cb = (u16*)C;
#pragma unroll
    for (int i = 0; i < 4; ++i) {
#pragma unroll
      for (int j = 0; j < 4; ++j)
#pragma unroll
        for (int r = 0; r < 4; ++r)
          scr[(quad * 4 + r) * 72 + j * 16 + l15] = f2bf(acc[i][j][r] + bvj[j]);
#pragma unroll
      for (int u = lane; u < 128; u += 64) {
        const int row = u >> 3, gr = u & 7;
        int4 vv = *(const int4*)(scr + row * 72 + gr * 8);
        *(int4*)(Cb + (m0 + wr + i * 16 + row) * (size_t)N + n0 + wc + gr * 8) = vv;
      }
    }
  }
}

// ---------------- windowed attention ----------------
// one block (4 waves) per (b, l, head). K staged in LDS (XOR-64), V^T and P at
// stride 208 (2-way banks = free). LDS total 79.2 KB -> 2 blocks/CU.
__global__ __launch_bounds__(256, 2) void attn_win(
    const u16* __restrict__ qkv, u16* __restrict__ o)
{
  __shared__ u16 Ks[196 * 64];      // slot16B = row*8 + (g ^ (row&7))
  __shared__ u16 Vt[64 * 208];      // Vt[d][n], cols >=196 zero
  __shared__ u16 Pb[4][16 * 208];   // per-wave strip
  __shared__ int gtok[208];

  const int bid = blockIdx.x;
  const int h = bid % 12;
  const int l = (bid / 12) % 16;
  const int b = bid / 192;
  const int wr0 = (l >> 2) * 14, wc0 = (l & 3) * 14;
  const int baseTok = b * 3136;

  const int t = threadIdx.x, wave = t >> 6, lane = t & 63;
  const int quad = lane >> 4, l15 = lane & 15;

  if (t < 208) {
    const int nn = t < 196 ? t : 195;
    gtok[t] = baseTok + (wr0 + nn / 14) * 56 + wc0 + nn % 14;
  }
  __syncthreads();

  // stage K (rows 0..195, 8 d-groups, XOR layout)
  for (int u = t; u < 196 * 8; u += 256) {
    const int row = u >> 3, gg = u & 7;
    int4 kv = *(const int4*)(qkv + (size_t)gtok[row] * 2304 + 768 + h * 64 + gg * 8);
    *(int4*)(Ks + (row * 8 + (gg ^ (row & 7))) * 8) = kv;
  }
  // stage V transposed: Vt[d][n]
  for (int u = t; u < 208 * 8; u += 256) {
    const int n = u >> 3, dg = u & 7;
    int4 vv = {0, 0, 0, 0};
    if (n < 196)
      vv = *(const int4*)(qkv + (size_t)gtok[n] * 2304 + 1536 + h * 64 + dg * 8);
    const u16* pv = (const u16*)&vv;
#pragma unroll
    for (int j = 0; j < 8; ++j) Vt[(dg * 8 + j) * 208 + n] = pv[j];
  }
  __syncthreads();

  u16* Pw = &Pb[wave][0];
  const bf16x8 zerov = {};

  for (int rt = wave; rt < 13; rt += 4) {
    const int n0r = rt * 16;
    int qn = n0r + l15; if (qn > 195) qn = 195;
    const u16* qrow = qkv + (size_t)gtok[qn] * 2304 + h * 64;
    const bf16x8 aq0 = *(const bf16x8*)(qrow + quad * 8);
    const bf16x8 aq1 = *(const bf16x8*)(qrow + 32 + quad * 8);

    floatx4 s[13];
#pragma unroll
    for (int ct = 0; ct < 13; ++ct) {
      int kr = ct * 16 + l15; if (kr > 195) kr = 195;
      const bf16x8 bk0 = *(const bf16x8*)(Ks + (kr * 8 + (quad ^ (kr & 7))) * 8);
      const bf16x8 bk1 = *(const bf16x8*)(Ks + (kr * 8 + ((quad + 4) ^ (kr & 7))) * 8);
      floatx4 z = {};
      z = __builtin_amdgcn_mfma_f32_16x16x32_bf16(aq0, bk0, z, 0, 0, 0);
      z = __builtin_amdgcn_mfma_f32_16x16x32_bf16(aq1, bk1, z, 0, 0, 0);
      s[ct] = z;
    }

    // softmax: col = ct*16+l15, rows = n0r + quad*4 + r
    float mx[4], sm[4];
#pragma unroll
    for (int r = 0; r < 4; ++r) mx[r] = -3e38f;
#pragma unroll
    for (int ct = 0; ct < 13; ++ct) {
      const bool maskct = (ct == 12) && (l15 >= 4);
#pragma unroll
      for (int r = 0; r < 4; ++r) {
        float v = s[ct][r] * 0.125f;
        if (maskct) v = -3e38f;
        s[ct][r] = v;
        mx[r] = fmaxf(mx[r], v);
      }
    }
#pragma unroll
    for (int r = 0; r < 4; ++r)
      for (int off = 1; off < 16; off <<= 1)
        mx[r] = fmaxf(mx[r], __shfl_xor(mx[r], off, 64));
#pragma unroll
    for (int r = 0; r < 4; ++r) sm[r] = 0.0f;
#pragma unroll
    for (int ct = 0; ct < 13; ++ct)
#pragma unroll
      for (int r = 0; r < 4; ++r) {
        const float p = __expf(s[ct][r] - mx[r]);
        s[ct][r] = p;
        sm[r] += p;
      }
#pragma unroll
    for (int r = 0; r < 4; ++r)
      for (int off = 1; off < 16; off <<= 1)
        sm[r] += __shfl_xor(sm[r], off, 64);

    // P -> LDS (A-layout round trip); cols 0..207 fully covered
#pragma unroll
    for (int ct = 0; ct < 13; ++ct)
#pragma unroll
      for (int r = 0; r < 4; ++r)
        Pw[(quad * 4 + r) * 208 + ct * 16 + l15] = f2bf(s[ct][r]);

    // O = P @ V: 6 full K=32 steps + masked tail (k 192..207 real)
    floatx4 oacc[4] = {};
#pragma unroll
    for (int ks = 0; ks < 6; ++ks) {
      const bf16x8 ap = *(const bf16x8*)(Pw + l15 * 208 + ks * 32 + quad * 8);
#pragma unroll
      for (int nt = 0; nt < 4; ++nt) {
        const bf16x8 bv = *(const bf16x8*)(Vt + (nt * 16 + l15) * 208 + ks * 32 + quad * 8);
        oacc[nt] = __builtin_amdgcn_mfma_f32_16x16x32_bf16(ap, bv, oacc[nt], 0, 0, 0);
      }
    }
    {
      const int off = 192 + (quad & 1) * 8;
      bf16x8 ap = *(const bf16x8*)(Pw + l15 * 208 + off);
      if (quad >= 2) ap = zerov;
#pragma unroll
      for (int nt = 0; nt < 4; ++nt) {
        const bf16x8 bv = *(const bf16x8*)(Vt + (nt * 16 + l15) * 208 + off);
        oacc[nt] = __builtin_amdgcn_mfma_f32_16x16x32_bf16(ap, bv, oacc[nt], 0, 0, 0);
      }
    }

    float rs[4];
#pragma unroll
    for (int r = 0; r < 4; ++r) rs[r] = 1.0f / sm[r];

    // O -> Pw repack -> coalesced 16B stores
#pragma unroll
    for (int nt = 0; nt < 4; ++nt)
#pragma unroll
      for (int r = 0; r < 4; ++r)
        Pw[(quad * 4 + r) * 208 + nt * 16 + l15] = f2bf(oacc[nt][r] * rs[r]);
#pragma unroll
    for (int u = lane; u < 128; u += 64) {
      const int row = u >> 3, gr = u & 7;
      const int n = n0r + row;
      if (n < 196) {
        int4 vv = *(const int4*)(Pw + row * 208 + gr * 8);
        *(int4*)(o + (size_t)gtok[n] * 768 + h * 64 + gr * 8) = vv;
      }
    }
  }
}

extern "C" void kernel_launch(void* const* d_in, const int* in_sizes, int n_in,
                              void* d_out, int out_size, void* d_ws, size_t ws_size,
                              hipStream_t stream)
{
  const void* x     = d_in[0];  // [8,3136,768]   fp32 or bf16
  const void* wqkv  = d_in[1];  // [768,2304]
  const void* wproj = d_in[2];  // [768,768]
  const void* bproj = d_in[3];  // [768]

  char* ws = (char*)d_ws;
  int*   flag   = (int*)ws;                         // 16 B
  float* bprojF = (float*)(ws + 16);                // 768 f32
  u16*   wqkvT  = (u16*)(ws + 4096);                // 2304*768 bf16
  u16*   wprojT = (u16*)(ws + 3543040);             // 768*768  bf16
  u16*   qkvbuf = (u16*)(ws + 4722688);             // 25088*2304 bf16
  u16*   xb     = (u16*)(ws + 120328192);           // 25088*768 bf16 (reused as attn out)
  u16*   attno  = xb;

  detect_k<<<1, 256, 0, stream>>>((const u16*)wqkv, flag);
  cast_x_k<<<dim3(18816), 256, 0, stream>>>(x, xb, 4816896, flag);
  ct_transpose_k<<<dim3(72, 24), 256, 0, stream>>>(wqkv, wqkvT, 768, 2304, flag);
  ct_transpose_k<<<dim3(24, 24), 256, 0, stream>>>(wproj, wprojT, 768, 768, flag);
  bias_cast_k<<<dim3(3), 256, 0, stream>>>(bproj, bprojF, 768, flag);

  gemm_bt<<<dim3(196 * 18), 256, 0, stream>>>(xb, wqkvT, (const float*)nullptr, qkvbuf,
                                              25088, 2304, 768, flag, 0, 18);
  attn_win<<<dim3(1536), 256, 0, stream>>>(qkvbuf, attno);
  gemm_bt<<<dim3(196 * 6), 256, 0, stream>>>(attno, wprojT, bprojF, d_out,
                                             25088, 768, 768, flag, 1, 6);
}